// Round 4
// baseline (4161.593 us; speedup 1.0000x reference)
//
#include <hip/hip_runtime.h>
#include <stdint.h>

#define DEVI __device__ __forceinline__

typedef unsigned short u16;
typedef __bf16 bf16x8 __attribute__((ext_vector_type(8)));
typedef float f32x4 __attribute__((ext_vector_type(4)));
typedef u16 u16x8 __attribute__((ext_vector_type(8)));
typedef u16 u16x4 __attribute__((ext_vector_type(4)));

DEVI u16 f2bf(float f){
  union { float f; unsigned u; } v; v.f = f;
  unsigned r = v.u + 0x7FFFu + ((v.u >> 16) & 1u);
  return (u16)(r >> 16);
}
DEVI float bf2f(u16 h){
  union { unsigned u; float f; } v; v.u = ((unsigned)h) << 16;
  return v.f;
}
DEVI float lky(float t){ return t > 0.f ? t : 0.2f * t; }

#define GLD16(gp, lp) __builtin_amdgcn_global_load_lds( \
    (const __attribute__((address_space(1))) void*)(gp), \
    (__attribute__((address_space(3))) void*)(lp), 16, 0, 0)

// ===========================================================================
// 256x256 8-phase GEMM, A read DIRECTLY as f32 (reg-staged, cvt, swizzled
// ds_write), B bf16 via global_load_lds with pre-swizzled source.
// C[n][o] = sum_k A[o][k]*B[n][k].  BK=64, 512 thr = 8 waves (2M x 4N).
// launch_bounds(512,1): LDS=128KiB caps at 1 block/CU anyway; (512,2) in R3
// capped VGPR at 128 -> acc spill -> 264MB scratch writes (the regression).
// VM issue order/iter: ph3 A8 | ph4 B2 | ph5 B2 | ph7 A8 | ph8 B4
//   -> vmcnt(10) @ph4 (enforces B(c1), staged prev ph8)
//   -> vmcnt(12) @ph8 (enforces B(next c0), staged ph4/ph5)
// ===========================================================================

template<int VM>
DEVI void PH(bf16x8 (&afr)[4], bf16x8 (&bfr)[4], f32x4 (&acc)[8][4], int H)
{
  __builtin_amdgcn_s_barrier();
  asm volatile("s_waitcnt lgkmcnt(0)" ::: "memory");
  __builtin_amdgcn_sched_barrier(0);
  __builtin_amdgcn_s_setprio(1);
  #pragma unroll
  for (int m = 0; m < 4; ++m)
    #pragma unroll
    for (int n = 0; n < 4; ++n)
      acc[H*4+m][n] = __builtin_amdgcn_mfma_f32_16x16x32_bf16(
          afr[m], bfr[n], acc[H*4+m][n], 0, 0, 0);
  __builtin_amdgcn_s_setprio(0);
  if constexpr (VM == 10){
    __builtin_amdgcn_sched_barrier(0);
    asm volatile("s_waitcnt vmcnt(10)" ::: "memory");
  } else if constexpr (VM == 12){
    __builtin_amdgcn_sched_barrier(0);
    asm volatile("s_waitcnt vmcnt(12)" ::: "memory");
  }
  __builtin_amdgcn_s_barrier();
}

// EPI 0: C[n*ldc+o] = acc
// EPI 2: C[n*ldc+o] = leaky(acc*scale[o]+off[o])
// EPI 3: val=leaky(acc+bias[o]); oacc[(q*4+o4)*4+m] += llw[o4*8976+o]*val
template<int EPI, int STACKED>
__global__ __launch_bounds__(512, 1)
void gemmF(const float* __restrict__ A, const u16* __restrict__ B,
           int Astride, int Kreal, int Kp, int Mrows, int Nt, int SN, int Mreal,
           float* __restrict__ C, long long ldc,
           const float* __restrict__ bias, const float* __restrict__ scale,
           const float* __restrict__ off, const float* __restrict__ llw,
           float* __restrict__ oacc)
{
  __shared__ __align__(16) u16 As[2][16384];
  __shared__ __align__(16) u16 Bs[2][16384];
  const int t    = threadIdx.x;
  const int lane = t & 63;
  const int wid  = t >> 6;
  const int wr = wid >> 2, wc = wid & 3;
  const int l4 = lane >> 4, l15 = lane & 15;

  // bijective XCD swizzle
  const int nwg = gridDim.x;
  const int xc = blockIdx.x & 7, pp = blockIdx.x >> 3;
  const int qq = nwg >> 3, rr = nwg & 7;
  const int wg = (xc < rr ? xc*(qq+1) : rr*(qq+1) + (xc-rr)*qq) + pp;
  // supertile: strips of (Mt x SN) so an XCD chunk spans many mt, few nt
  const int strip_sz = (nwg / Nt) * SN;
  const int strip = wg / strip_sz, srem = wg % strip_sz;
  const int mt = srem / SN, nt = strip*SN + srem % SN;

  const int am0 = mt*256;
  const int bn0 = nt*256;

  f32x4 acc[8][4];
  #pragma unroll
  for (int i = 0; i < 8; ++i)
    #pragma unroll
    for (int j = 0; j < 4; ++j) acc[i][j] = f32x4{0.f,0.f,0.f,0.f};
  bf16x8 afr[4], bfr[4];
  f32x4 ra[8];

  const int NT2 = Kp >> 6;   // even
  const int NI  = NT2 >> 1;

  // ---- helpers --------------------------------------------------------
  auto BSTAGE = [&](int tile, int buf, int h){   // 2 x GLD16, half h
    const int kc = tile*64;
    u16* lbase = (buf ? &Bs[1][0] : &Bs[0][0]) + h*8192;
    #pragma unroll
    for (int j = 0; j < 2; ++j){
      const int u = j*512 + t;
      const int rl = u >> 3, sl = u & 7;
      const u16* gp = B + (size_t)(bn0 + h*128 + rl)*Kp + kc + ((sl ^ (rl & 7))*8);
      GLD16(gp, lbase + u*8);
    }
  };
  auto ALOAD = [&](int tile){                    // 8 x f32x4 loads
    const int kc = tile*64;
    #pragma unroll
    for (int j = 0; j < 8; ++j){
      const int h = j >> 2;
      const int u = (j & 3)*512 + t;
      const int row = am0 + h*128 + (u >> 4);
      const int col = kc + (u & 15)*4;
      int ro = row, ko = 0;
      if (STACKED){ if (row >= 8976){ ro = row - 8976; ko = 4424; } }
      const bool ok = (row < Mrows) && (col < Kreal);
      const float* p = A + (size_t)(ok ? ro : 0)*Astride + ko + (ok ? col : 0);
      f32x4 v = *(const f32x4*)p;
      ra[j] = ok ? v : f32x4{0.f,0.f,0.f,0.f};
    }
  };
  auto AWRITE_H = [&](int buf, int h){           // 4 x ds_write_b64, half h
    u16* lb = buf ? &As[1][0] : &As[0][0];
    #pragma unroll
    for (int jj = 0; jj < 4; ++jj){
      const int j = h*4 + jj;
      const int u = jj*512 + t;
      const int rl = h*128 + (u >> 4);
      const int cu = u & 15, koct = cu >> 1, hu = cu & 1;
      f32x4 v = ra[j];
      u16x4 w = { f2bf(v[0]), f2bf(v[1]), f2bf(v[2]), f2bf(v[3]) };
      *(u16x4*)&lb[rl*64 + ((koct ^ (rl & 7))*8) + hu*4] = w;
    }
  };
  auto RDA = [&](int buf, int h, int ks){
    const u16* lb = buf ? &As[1][0] : &As[0][0];
    #pragma unroll
    for (int m = 0; m < 4; ++m){
      const int r = wr*128 + h*64 + m*16 + l15;
      afr[m] = *(const bf16x8*)&lb[r*64 + (((ks*4 + l4) ^ (r & 7))*8)];
    }
  };
  auto RDB = [&](int buf, int ks){
    const u16* lb = buf ? &Bs[1][0] : &Bs[0][0];
    #pragma unroll
    for (int n = 0; n < 4; ++n){
      const int r = wc*64 + n*16 + l15;
      bfr[n] = *(const bf16x8*)&lb[r*64 + (((ks*4 + l4) ^ (r & 7))*8)];
    }
  };
  #define FENCE asm volatile("" ::: "memory")

  // ---- prologue: issue stream A8(t0), B4(t0), [AWRITE t0], B4(t1), A8(t1)
  ALOAD(0);                 FENCE;
  BSTAGE(0,0,0); BSTAGE(0,0,1);  FENCE;
  AWRITE_H(0,0); AWRITE_H(0,1);  FENCE;   // compiler waits A8(t0) here
  BSTAGE(1,1,0); BSTAGE(1,1,1);  FENCE;
  ALOAD(1);                 FENCE;
  asm volatile("s_waitcnt vmcnt(12)" ::: "memory");  // enforce B(t0)
  asm volatile("s_waitcnt lgkmcnt(0)" ::: "memory");
  __builtin_amdgcn_s_barrier();

  for (int i = 0; i < NI; ++i){
    const int ta = (2*i+2 < NT2) ? 2*i+2 : NT2-1;
    const int tb = (2*i+3 < NT2) ? 2*i+3 : NT2-1;
    // ph1: write A(c1)->b1 h0 | read b0 H0 ks0 + B ks0 | MFMA
    AWRITE_H(1,0);
    RDA(0,0,0); RDB(0,0);
    PH<-1>(afr, bfr, acc, 0);
    // ph2
    AWRITE_H(1,1);
    RDA(0,1,0);
    PH<-1>(afr, bfr, acc, 1);
    // ph3: issue A-loads(ta)
    RDA(0,0,1); RDB(0,1);
    ALOAD(ta);
    PH<-1>(afr, bfr, acc, 0);
    // ph4: stage B(ta) h0 ; vmcnt(10) enforces B(c1)
    RDA(0,1,1);
    BSTAGE(ta,0,0);
    PH<10>(afr, bfr, acc, 1);
    // ph5: write A(ta)->b0 h0 ; stage B(ta) h1
    AWRITE_H(0,0);
    RDA(1,0,0); RDB(1,0);
    BSTAGE(ta,0,1);
    PH<-1>(afr, bfr, acc, 0);
    // ph6
    AWRITE_H(0,1);
    RDA(1,1,0);
    PH<-1>(afr, bfr, acc, 1);
    // ph7: issue A-loads(tb)
    RDA(1,0,1); RDB(1,1);
    ALOAD(tb);
    PH<-1>(afr, bfr, acc, 0);
    // ph8: stage B(tb) both halves ; vmcnt(12) enforces B(ta)
    RDA(1,1,1);
    BSTAGE(tb,1,0); BSTAGE(tb,1,1);
    PH<12>(afr, bfr, acc, 1);
  }
  asm volatile("s_waitcnt vmcnt(0) lgkmcnt(0)" ::: "memory");

  const int ob0 = mt*256 + wr*128;
  const int nb0 = nt*256 + wc*64;

  if (EPI == 0){
    #pragma unroll
    for (int mi = 0; mi < 8; ++mi){
      const int ob = ob0 + mi*16 + l4*4;
      if (ob < Mreal){
        #pragma unroll
        for (int ni = 0; ni < 4; ++ni){
          const int n = nb0 + ni*16 + l15;
          *(f32x4*)&C[(size_t)n*ldc + ob] = acc[mi][ni];
        }
      }
    }
  } else if (EPI == 2){
    #pragma unroll
    for (int mi = 0; mi < 8; ++mi){
      const int ob = ob0 + mi*16 + l4*4;
      if (ob < Mreal){
        const float sc0=scale[ob],sc1=scale[ob+1],sc2=scale[ob+2],sc3=scale[ob+3];
        const float of0=off[ob],of1=off[ob+1],of2=off[ob+2],of3=off[ob+3];
        #pragma unroll
        for (int ni = 0; ni < 4; ++ni){
          const int n = nb0 + ni*16 + l15;
          f32x4 a = acc[mi][ni];
          f32x4 vv = { lky(a[0]*sc0+of0), lky(a[1]*sc1+of1),
                       lky(a[2]*sc2+of2), lky(a[3]*sc3+of3) };
          *(f32x4*)&C[(size_t)n*ldc + ob] = vv;
        }
      }
    }
  } else { // EPI == 3
    #pragma unroll
    for (int ni = 0; ni < 4; ++ni){
      float s0=0.f, s1=0.f, s2=0.f, s3=0.f;
      #pragma unroll
      for (int mi = 0; mi < 8; ++mi){
        #pragma unroll
        for (int r = 0; r < 4; ++r){
          const int o = ob0 + mi*16 + l4*4 + r;
          if (o < Mreal){
            const float val = lky(acc[mi][ni][r] + bias[o]);
            s0 += llw[o]         * val;
            s1 += llw[8976 + o]  * val;
            s2 += llw[17952 + o] * val;
            s3 += llw[26928 + o] * val;
          }
        }
      }
      const int n = nb0 + ni*16 + l15;
      const int q = n >> 2, m = n & 3;
      float sv[4] = {s0,s1,s2,s3};
      #pragma unroll
      for (int o4 = 0; o4 < 4; ++o4){
        float tt = sv[o4];
        tt += __shfl_xor(tt, 16);
        tt += __shfl_xor(tt, 32);
        if (l4 == 0) atomicAdd(&oacc[(q*4 + o4)*4 + m], tt);
      }
    }
  }
}

// ---------------------------------------------------------------------------
// Old 128x128 GEMM, kept only for the tiny v_pre GEMM (C[o][n]+bias)
// ---------------------------------------------------------------------------
__global__ __launch_bounds__(256)
void gemm_vpre(const u16* __restrict__ A, const u16* __restrict__ B,
               int Kp, int Nt, int Mreal, float* __restrict__ C, long long ldc,
               const float* __restrict__ bias)
{
  __shared__ __align__(16) u16 As[2][4096];
  __shared__ __align__(16) u16 Bs[2][4096];
  const int tid  = threadIdx.x;
  const int lane = tid & 63;
  const int wr   = (tid >> 6) >> 1, wc = (tid >> 6) & 1;
  const int l4   = lane >> 4, l15 = lane & 15;
  const int mt   = blockIdx.x / Nt, nt = blockIdx.x % Nt;

  const size_t arow = (size_t)(mt*128 + (tid>>2)) * Kp + (tid&3)*8;
  const size_t brow = (size_t)(nt*128 + (tid>>2)) * Kp + (tid&3)*8;
  const int    ldst = (tid>>2)*32 + (tid&3)*8;
  const size_t rowskip = (size_t)64 * Kp;

  f32x4 acc[4][4];
  #pragma unroll
  for (int i=0;i<4;i++)
    #pragma unroll
    for (int j=0;j<4;j++) acc[i][j] = f32x4{0.f,0.f,0.f,0.f};

  const int NT = Kp >> 5;
  {
    const u16* a0 = A + arow; const u16* b0 = B + brow;
    GLD16(a0,           &As[0][ldst]);
    GLD16(a0 + rowskip, &As[0][ldst + 2048]);
    GLD16(b0,           &Bs[0][ldst]);
    GLD16(b0 + rowskip, &Bs[0][ldst + 2048]);
  }
  __syncthreads();

  for (int kt=0; kt<NT; ++kt){
    const int cur = kt & 1;
    if (kt + 1 < NT){
      const u16* a0 = A + arow + (size_t)(kt+1)*32;
      const u16* b0 = B + brow + (size_t)(kt+1)*32;
      GLD16(a0,           &As[cur^1][ldst]);
      GLD16(a0 + rowskip, &As[cur^1][ldst + 2048]);
      GLD16(b0,           &Bs[cur^1][ldst]);
      GLD16(b0 + rowskip, &Bs[cur^1][ldst + 2048]);
    }
    bf16x8 af[4], bf[4];
    #pragma unroll
    for (int mi=0;mi<4;mi++)
      af[mi] = *(const bf16x8*)&As[cur][(wr*64 + mi*16 + l15)*32 + l4*8];
    #pragma unroll
    for (int ni=0;ni<4;ni++)
      bf[ni] = *(const bf16x8*)&Bs[cur][(wc*64 + ni*16 + l15)*32 + l4*8];
    #pragma unroll
    for (int mi=0;mi<4;mi++)
      #pragma unroll
      for (int ni=0;ni<4;ni++)
        acc[mi][ni] = __builtin_amdgcn_mfma_f32_16x16x32_bf16(af[mi], bf[ni], acc[mi][ni], 0, 0, 0);
    __syncthreads();
  }

  const int ob0 = mt*128 + wr*64;
  const int nb0 = nt*128 + wc*64;
  #pragma unroll
  for (int mi=0;mi<4;mi++)
    #pragma unroll
    for (int r=0;r<4;r++){
      const int o = ob0 + mi*16 + l4*4 + r;
      if (o < Mreal){
        const float bb = bias[o];
        #pragma unroll
        for (int ni=0;ni<4;ni++){
          const int n = nb0 + ni*16 + l15;
          C[(size_t)o*ldc + n] = acc[mi][ni][r] + bb;
        }
      }
    }
}

// --- f32 -> bf16 padded convert (small uses only) ---------------------------
__global__ void k_cvt_pad(const float* __restrict__ src, int srows, int scols,
                          int lds_, int koff, u16* __restrict__ dst, int Kp)
{
  const int r = blockIdx.x;
  const int nch = Kp >> 3;
  for (int ch = threadIdx.x; ch < nch; ch += blockDim.x){
    const int k = ch*8;
    u16 o[8];
    if (r < srows){
      #pragma unroll
      for (int i=0;i<8;i++){
        const int kk = k + i;
        o[i] = (kk < scols) ? f2bf(src[(size_t)r*lds_ + koff + kk]) : (u16)0;
      }
    } else {
      #pragma unroll
      for (int i=0;i<8;i++) o[i] = 0;
    }
    u16x8 vv = { o[0],o[1],o[2],o[3],o[4],o[5],o[6],o[7] };
    *(u16x8*)&dst[(size_t)r*Kp + k] = vv;
  }
}

// --- objB: rows 0..639 = bf16(obj), rows 640..1279 = bf16(|obj|), K pad 4480
__global__ void k_cvt_obj(const float* __restrict__ obj, u16* __restrict__ dst)
{
  const int r = blockIdx.x;
  const int ab = (r >= 640);
  const float* src = obj + (size_t)(ab ? r-640 : r)*4424;
  for (int ch = threadIdx.x; ch < 560; ch += 256){
    const int k = ch*8;
    u16 o[8];
    #pragma unroll
    for (int i=0;i<8;i++){
      const int kk = k+i;
      float f = (kk < 4424) ? src[kk] : 0.f;
      if (ab) f = fabsf(f);
      o[i] = f2bf(f);
    }
    u16x8 vv = { o[0],o[1],o[2],o[3],o[4],o[5],o[6],o[7] };
    *(u16x8*)&dst[(size_t)r*4480 + k] = vv;
  }
}

// --- P12 combine ------------------------------------------------------------
__global__ void k_combine(const float* __restrict__ U, const int* __restrict__ rel,
                          float* __restrict__ P12)
{
  const int q = blockIdx.x;
  const int i1 = rel[q*2], i2 = rel[q*2+1];
  const float* u1  = U + (size_t)i1*17952;
  const float* u2  = U + (size_t)i2*17952 + 8976;
  const float* u1a = U + (size_t)(640+i1)*17952;
  const float* u2a = U + (size_t)(640+i2)*17952 + 8976;
  float* p1 = P12 + (size_t)q*8976;
  float* p2 = P12 + (size_t)(1024+q)*8976;
  for (int c = threadIdx.x*4; c < 8976; c += 1024){
    f32x4 a  = *(const f32x4*)&u1[c];
    f32x4 b  = *(const f32x4*)&u2[c];
    f32x4 aa = *(const f32x4*)&u1a[c];
    f32x4 bb = *(const f32x4*)&u2a[c];
    *(f32x4*)&p1[c] = a + b;
    *(f32x4*)&p2[c] = aa + bb;
  }
}

// --- x (B,256,1024) -> xT bf16 [(b*1024+s)][c] ------------------------------
__global__ void k_xT(const float* __restrict__ x, u16* __restrict__ xT)
{
  __shared__ float t[32][33];
  const int bid = blockIdx.x;
  const int b = bid >> 8; const int cs = (bid >> 5) & 7; const int ss = bid & 31;
  const int tx = threadIdx.x & 31, ty = threadIdx.x >> 5;
  #pragma unroll
  for (int i=0;i<4;i++){
    const int r = ty + i*8;
    t[r][tx] = x[((size_t)(b*256 + cs*32 + r))*1024 + ss*32 + tx];
  }
  __syncthreads();
  #pragma unroll
  for (int i=0;i<4;i++){
    const int r = ty + i*8;
    xT[((size_t)(b*1024 + ss*32 + r))*256 + cs*32 + tx] = f2bf(t[tx][r]);
  }
}

// --- y = fc_w@xr ; mask = sigmoid(y) ----------------------------------------
__global__ void k_ymask(const float* __restrict__ x, const float* __restrict__ fcw,
                        float* __restrict__ y, float* __restrict__ mask)
{
  __shared__ float fc[1024];
  const int b = blockIdx.x >> 2, st = blockIdx.x & 3;
  for (int i=threadIdx.x; i<1024; i+=256) fc[i] = fcw[i];
  __syncthreads();
  const int s = st*256 + threadIdx.x;
  float a0=0,a1=0,a2=0,a3=0;
  for (int c=0;c<256;c++){
    const float xv = x[((size_t)(b*256+c))*1024 + s];
    a0 += fc[c]*xv; a1 += fc[256+c]*xv; a2 += fc[512+c]*xv; a3 += fc[768+c]*xv;
  }
  const size_t base = (size_t)(b*4)*1024 + s;
  y[base]        = a0; mask[base]        = 1.f/(1.f+expf(-a0));
  y[base+1024]   = a1; mask[base+1024]   = 1.f/(1.f+expf(-a1));
  y[base+2048]   = a2; mask[base+2048]   = 1.f/(1.f+expf(-a2));
  y[base+3072]   = a3; mask[base+3072]   = 1.f/(1.f+expf(-a3));
}

__global__ void k_out1(const float* __restrict__ y, float* __restrict__ out1){
  const int bn = blockIdx.x;
  float m = -3.4e38f;
  for (int s=threadIdx.x; s<1024; s+=256) m = fmaxf(m, y[(size_t)bn*1024+s]);
  for (int o=32;o;o>>=1) m = fmaxf(m, __shfl_xor(m,o));
  __shared__ float red[4];
  if ((threadIdx.x&63)==0) red[threadIdx.x>>6] = m;
  __syncthreads();
  if (threadIdx.x==0) out1[bn] = fmaxf(fmaxf(red[0],red[1]),fmaxf(red[2],red[3]));
}

// --- v[b,j,m] = sum_s vpreT[j][b*1024+s]*mask[b,m,s] ------------------------
__global__ void k_v(const float* __restrict__ vpreT, const float* __restrict__ mask,
                    float* __restrict__ v){
  const int b = blockIdx.x >> 7, j = blockIdx.x & 127;
  float a[4]={0,0,0,0};
  for (int s=threadIdx.x; s<1024; s+=256){
    const float pv = vpreT[(size_t)j*8192 + b*1024 + s];
    #pragma unroll
    for (int m=0;m<4;m++) a[m] += pv * mask[((size_t)(b*4+m))*1024 + s];
  }
  __shared__ float red[4][5];
  #pragma unroll
  for (int m=0;m<4;m++){
    float t=a[m];
    for (int o=32;o;o>>=1) t += __shfl_xor(t,o);
    if ((threadIdx.x&63)==0) red[m][threadIdx.x>>6]=t;
  }
  __syncthreads();
  if (threadIdx.x<4)
    v[(size_t)(b*128+j)*4 + threadIdx.x] =
      red[threadIdx.x][0]+red[threadIdx.x][1]+red[threadIdx.x][2]+red[threadIdx.x][3];
}

// --- lv[b,j,n] = leaky(sum_m A[n,m]*v[b,j,m]) -------------------------------
__global__ void k_lv(const float* __restrict__ Am, const float* __restrict__ v,
                     float* __restrict__ lv){
  const int idx = blockIdx.x*256 + threadIdx.x;
  if (idx < 1024){
    #pragma unroll
    for (int n=0;n<4;n++){
      float s=0;
      #pragma unroll
      for (int m=0;m<4;m++) s += Am[n*4+m]*v[idx*4+m];
      lv[idx*4+n] = lky(s);
    }
  }
}

// --- sV[b,o,n] = sum_j sw_w[o,8848+j]*lv[b,j,n] -----------------------------
__global__ void k_sV(const float* __restrict__ sw, const float* __restrict__ lv,
                     float* __restrict__ sV){
  __shared__ float l[4096];
  for (int i=threadIdx.x; i<4096; i+=256) l[i]=lv[i];
  __syncthreads();
  const int o = blockIdx.x*256 + threadIdx.x;
  if (o >= 8976) return;
  float acc[8][4] = {};
  const float* row = sw + (size_t)o*8976 + 8848;
  for (int j=0;j<128;j++){
    const float wv = row[j];
    #pragma unroll
    for (int b=0;b<8;b++){
      const float* lb = &l[(b*128+j)*4];
      #pragma unroll
      for (int n=0;n<4;n++) acc[b][n] += wv*lb[n];
    }
  }
  #pragma unroll
  for (int b=0;b<8;b++){
    f32x4 vv = {acc[b][0],acc[b][1],acc[b][2],acc[b][3]};
    *(f32x4*)&sV[((size_t)b*8976 + o)*4] = vv;
  }
}

// --- BN fold ----------------------------------------------------------------
__global__ void k_so(const float* __restrict__ cgb, const float* __restrict__ g,
                     const float* __restrict__ b2, const float* __restrict__ m,
                     const float* __restrict__ vvar, float* __restrict__ so){
  const int o = blockIdx.x*256+threadIdx.x;
  if (o<8976){
    const float sc = g[o]*rsqrtf(vvar[o]+1e-5f);
    so[o]=sc; so[8976+o] = (cgb[o]-m[o])*sc + b2[o];
  }
}

// --- glbB (bf16 mean_n hg, K pad 9088) + t2 ---------------------------------
__global__ void k_glb_t2(const float* __restrict__ P12, const float* __restrict__ obj,
                         const int* __restrict__ rel,
                         const float* __restrict__ sV, const float* __restrict__ swb,
                         const float* __restrict__ v, const float* __restrict__ Am,
                         const float* __restrict__ cow, u16* __restrict__ glbB,
                         float* __restrict__ t2)
{
  const int q = blockIdx.x; const int b = q >> 7;
  const int i1 = rel[q*2], i2 = rel[q*2+1];
  const float* o1 = obj + (size_t)i1*4424;
  const float* o2 = obj + (size_t)i2*4424;
  float rA[4], aA[4];
  #pragma unroll
  for (int n=0;n<4;n++){
    const float s = Am[n*4]+Am[n*4+1]+Am[n*4+2]+Am[n*4+3];
    rA[n]=0.6f*s; aA[n]=0.4f*fabsf(s);
  }
  float t2a[16] = {};
  for (int c = threadIdx.x; c < 9088; c += 256){
    if (c < 8976){
      const float p1 = P12[(size_t)q*8976 + c];
      const float p2 = P12[(size_t)(1024+q)*8976 + c];
      const f32x4 sv = *(const f32x4*)&sV[((size_t)b*8976 + c)*4];
      const float sb = swb[c];
      const float gs = (c < 4424) ? o1[c] : (c < 8848) ? o2[c-4424] : 0.f;
      float hg[4]; float sum = 0.f;
      #pragma unroll
      for (int n=0;n<4;n++){
        const float xs2 = lky(rA[n]*p1 + aA[n]*p2 + sv[n] + sb);
        const float g = (c < 8848) ? gs : v[((size_t)b*128 + (c-8848))*4 + n];
        hg[n] = g + xs2; sum += hg[n];
      }
      glbB[(size_t)q*9088 + c] = f2bf(0.25f*sum);
      #pragma unroll
      for (int o4=0;o4<4;o4++){
        const float cw = cow[(size_t)o4*17952 + 8976 + c];
        #pragma unroll
        for (int n=0;n<4;n++) t2a[o4*4+n] += cw*hg[n];
      }
    } else {
      glbB[(size_t)q*9088 + c] = 0;
    }
  }
  __shared__ float red[16][5];
  #pragma unroll
  for (int i=0;i<16;i++){
    float t = t2a[i];
    for (int o=32;o;o>>=1) t += __shfl_xor(t,o);
    if ((threadIdx.x&63)==0) red[i][threadIdx.x>>6]=t;
  }
  __syncthreads();
  if (threadIdx.x < 16)
    t2[q*16+threadIdx.x] = red[threadIdx.x][0]+red[threadIdx.x][1]
                          +red[threadIdx.x][2]+red[threadIdx.x][3];
}

// --- adj --------------------------------------------------------------------
__global__ void k_adj(const float* __restrict__ glb2, const float* __restrict__ cow,
                      const float* __restrict__ t2, const float* __restrict__ cob,
                      float* __restrict__ adj)
{
  const int q = blockIdx.x;
  float a[4]={0,0,0,0};
  for (int c=threadIdx.x; c<8976; c+=256){
    const float g = glb2[(size_t)q*8976+c];
    #pragma unroll
    for (int o=0;o<4;o++) a[o] += cow[(size_t)o*17952 + c]*g;
  }
  __shared__ float red[4][5]; __shared__ float co1[4];
  #pragma unroll
  for (int i=0;i<4;i++){
    float t=a[i]; for (int o=32;o;o>>=1) t += __shfl_xor(t,o);
    if ((threadIdx.x&63)==0) red[i][threadIdx.x>>6]=t;
  }
  __syncthreads();
  if (threadIdx.x<4)
    co1[threadIdx.x]=red[threadIdx.x][0]+red[threadIdx.x][1]+red[threadIdx.x][2]+red[threadIdx.x][3];
  __syncthreads();
  if (threadIdx.x<16){
    const int a_=threadIdx.x>>2, m=threadIdx.x&3;
    const float t = co1[a_] + t2[q*16 + a_*4 + m] + cob[a_];
    adj[q*16 + a_*4 + m] = 1.f/(1.f+expf(-t));
  }
}

// --- hd_b[(q*4+m)][c] bf16, K pad 9088 --------------------------------------
__global__ void k_hd(const float* __restrict__ P12, const float* __restrict__ obj,
                     const int* __restrict__ rel,
                     const float* __restrict__ sV, const float* __restrict__ swb,
                     const float* __restrict__ v, const float* __restrict__ Am,
                     const float* __restrict__ adj, u16* __restrict__ hdb)
{
  const int q = blockIdx.x; const int b = q>>7;
  const int i1 = rel[q*2], i2 = rel[q*2+1];
  const float* o1 = obj + (size_t)i1*4424;
  const float* o2 = obj + (size_t)i2*4424;
  float rA[4], aA[4];
  #pragma unroll
  for (int n=0;n<4;n++){
    const float s = Am[n*4]+Am[n*4+1]+Am[n*4+2]+Am[n*4+3];
    rA[n]=0.6f*s; aA[n]=0.4f*fabsf(s);
  }
  __shared__ float aj[16];
  if (threadIdx.x<16) aj[threadIdx.x] = adj[q*16+threadIdx.x];
  __syncthreads();
  float ajr[16];
  #pragma unroll
  for (int i=0;i<16;i++) ajr[i]=aj[i];
  for (int c=threadIdx.x; c<9088; c+=256){
    if (c<8976){
      const float p1 = P12[(size_t)q*8976 + c];
      const float p2 = P12[(size_t)(1024+q)*8976 + c];
      const f32x4 sv = *(const f32x4*)&sV[((size_t)b*8976 + c)*4];
      const float sb = swb[c];
      const float gs = (c < 4424) ? o1[c] : (c < 8848) ? o2[c-4424] : 0.f;
      float hg[4];
      #pragma unroll
      for (int n=0;n<4;n++){
        const float xs2 = lky(rA[n]*p1 + aA[n]*p2 + sv[n] + sb);
        const float g = (c < 8848) ? gs : v[((size_t)b*128 + (c-8848))*4 + n];
        hg[n] = g + xs2;
      }
      #pragma unroll
      for (int m=0;m<4;m++){
        const float hv = lky(hg[0]*ajr[m] + hg[1]*ajr[4+m] + hg[2]*ajr[8+m] + hg[3]*ajr[12+m]);
        hdb[((size_t)(q*4+m))*9088 + c] = f2bf(hv);
      }
    } else {
      #pragma unroll
      for (int m=0;m<4;m++) hdb[((size_t)(q*4+m))*9088 + c] = 0;
    }
  }
}

// --- final ------------------------------------------------------------------
__global__ void k_final(const float* __restrict__ o2f, const float* __restrict__ out1,
                        const float* __restrict__ llb, const float* __restrict__ mm,
                        float* __restrict__ out)
{
  const int idx = blockIdx.x*256+threadIdx.x;
  if (idx < 4096){
    const int q = idx>>2, o = idx&3, b = q>>7;
    float s=0.f;
    #pragma unroll
    for (int m=0;m<4;m++) s += lky(o2f[(q*4+o)*4+m] + llb[o]) * mm[o*4+m];
    out[idx] = 0.5f*(out1[b*4+o] + s);
  }
}

extern "C" void kernel_launch(void* const* d_in, const int* in_sizes, int n_in,
                              void* d_out, int out_size, void* d_ws, size_t ws_size,
                              hipStream_t stream)
{
  const float* x    = (const float*)d_in[0];
  const int*   rel  = (const int*)d_in[1];
  const float* obj  = (const float*)d_in[2];
  const float* fcw  = (const float*)d_in[3];
  const float* ctw  = (const float*)d_in[4];
  const float* ctb  = (const float*)d_in[5];
  const float* Am   = (const float*)d_in[6];
  const float* sww  = (const float*)d_in[7];
  const float* swb  = (const float*)d_in[8];
  const float* cgw  = (const float*)d_in[9];
  const float* cgb  = (const float*)d_in[10];
  const float* bng  = (const float*)d_in[11];
  const float* bnb  = (const float*)d_in[12];
  const float* bnm  = (const float*)d_in[13];
  const float* bnv  = (const float*)d_in[14];
  const float* cow  = (const float*)d_in[15];
  const float* cob  = (const float*)d_in[16];
  const float* dww  = (const float*)d_in[17];
  const float* dwb  = (const float*)d_in[18];
  const float* llw  = (const float*)d_in[19];
  const float* llb  = (const float*)d_in[20];
  const float* mm   = (const float*)d_in[21];
  float* out = (float*)d_out;
  (void)in_sizes; (void)n_in; (void)out_size; (void)ws_size;

  char* ws = (char*)d_ws;
  size_t off = 0;
  auto alloc = [&](size_t bytes)->char*{
    char* p = ws + off; off = (off + bytes + 255) & ~(size_t)255; return p;
  };
  char*  UG    = alloc((size_t)94371840);              // U  ∪  [glbB ; hdb]
  float* U     = (float*)UG;                           // 1280 x 17952 f32
  u16*   glbB  = (u16*)  UG;                           // 1024 x 9088 bf16
  u16*   hdb   = (u16*)  (UG + (size_t)1024*9088*2);   // 4096 x 9088 bf16
  u16*   objB  = (u16*)  alloc((size_t)1280*4480*2);
  float* P12   = (float*)alloc((size_t)2048*8976*4);
  float* glb2  = (float*)alloc((size_t)1024*8976*4);
  u16*   xT    = (u16*)  alloc((size_t)8192*256*2);
  u16*   ctwb  = (u16*)  alloc((size_t)128*256*2);
  float* y     = (float*)alloc((size_t)32768*4);
  float* mask  = (float*)alloc((size_t)32768*4);
  float* out1  = (float*)alloc((size_t)32*4);
  float* vpreT = (float*)alloc((size_t)128*8192*4);
  float* v     = (float*)alloc((size_t)4096*4);
  float* lv    = (float*)alloc((size_t)4096*4);
  float* sV    = (float*)alloc((size_t)287232*4);
  float* so    = (float*)alloc((size_t)2*8976*4);
  float* t2    = (float*)alloc((size_t)16384*4);
  float* adj   = (float*)alloc((size_t)16384*4);
  float* o2f   = (float*)alloc((size_t)16384*4);

  // stage 1: small precomputes
  k_xT<<<dim3(2048), dim3(256), 0, stream>>>(x, xT);
  k_cvt_pad<<<dim3(128), dim3(256), 0, stream>>>(ctw, 128, 256, 256, 0, ctwb, 256);
  k_ymask<<<dim3(32), dim3(256), 0, stream>>>(x, fcw, y, mask);
  k_out1<<<dim3(32), dim3(256), 0, stream>>>(y, out1);
  gemm_vpre<<<dim3(64), dim3(256), 0, stream>>>(
      ctwb, xT, 256, 64, 128, vpreT, (long long)8192, ctb);
  k_v<<<dim3(1024), dim3(256), 0, stream>>>(vpreT, mask, v);

  // stage 2: U = [W_F_left; W_F_right] @ [obj; |obj|]^T  (A = sww f32 direct)
  k_cvt_obj<<<dim3(1280), dim3(256), 0, stream>>>(obj, objB);
  gemmF<0,1><<<dim3(71*5), dim3(512), 0, stream>>>(
      sww, objB, 8976, 4424, 4480, 17952, 5, 5, 17952, U, (long long)17952,
      nullptr, nullptr, nullptr, nullptr, nullptr);
  k_combine<<<dim3(1024), dim3(256), 0, stream>>>(U, rel, P12);

  // stage 3: sV, glb, t2
  k_lv<<<dim3(4), dim3(256), 0, stream>>>(Am, v, lv);
  k_sV<<<dim3(36), dim3(256), 0, stream>>>(sww, lv, sV);
  k_glb_t2<<<dim3(1024), dim3(256), 0, stream>>>(P12, obj, rel, sV, swb, v, Am,
                                                 cow, glbB, t2);

  // stage 4: GEMM2  glb2 = leaky(BN(cg_w @ glb + cg_b))  (A = cgw f32 direct)
  k_so<<<dim3(36), dim3(256), 0, stream>>>(cgb, bng, bnb, bnm, bnv, so);
  gemmF<2,0><<<dim3(36*4), dim3(512), 0, stream>>>(
      cgw, glbB, 8976, 8976, 9088, 8976, 4, 4, 8976, glb2, (long long)8976,
      nullptr, so, so + 8976, nullptr, nullptr);

  // stage 5: adj, hd
  k_adj<<<dim3(1024), dim3(256), 0, stream>>>(glb2, cow, t2, cob, adj);
  k_hd<<<dim3(1024), dim3(256), 0, stream>>>(P12, obj, rel, sV, swb, v, Am, adj, hdb);

  // stage 6: GEMM3 fused with ll_w reduction  (A = dww f32 direct)
  hipMemsetAsync(o2f, 0, (size_t)16384*4, stream);
  gemmF<3,0><<<dim3(36*16), dim3(512), 0, stream>>>(
      dww, hdb, 8976, 8976, 9088, 8976, 16, 4, 8976, nullptr, 0,
      dwb, nullptr, nullptr, llw, o2f);

  // stage 7: final combine
  k_final<<<dim3(16), dim3(256), 0, stream>>>(o2f, out1, llb, mm, out);
}

// Round 5
// 2111.538 us; speedup vs baseline: 1.9709x; 1.9709x over previous
//
#include <hip/hip_runtime.h>
#include <stdint.h>

#define DEVI __device__ __forceinline__

typedef unsigned short u16;
typedef __bf16 bf16x8 __attribute__((ext_vector_type(8)));
typedef float f32x4 __attribute__((ext_vector_type(4)));
typedef u16 u16x8 __attribute__((ext_vector_type(8)));

DEVI u16 f2bf(float f){
  union { float f; unsigned u; } v; v.f = f;
  unsigned r = v.u + 0x7FFFu + ((v.u >> 16) & 1u);
  return (u16)(r >> 16);
}
DEVI float bf2f(u16 h){
  union { unsigned u; float f; } v; v.u = ((unsigned)h) << 16;
  return v.f;
}
DEVI float lky(float t){ return t > 0.f ? t : 0.2f * t; }

#define GLD16(gp, lp) __builtin_amdgcn_global_load_lds( \
    (const __attribute__((address_space(1))) void*)(gp), \
    (__attribute__((address_space(3))) void*)(lp), 16, 0, 0)

// ===========================================================================
// 256x256 8-phase bf16 GEMM (T2 swizzle + T3/T4 counted vmcnt + T5 setprio)
// C[n][o] = sum_k A[o][k]*B[n][k]; A,B row-major bf16, K-contiguous.
// BK=64, 512 threads = 8 waves (2M x 4N), per-wave 128x64 output.
// EXACT round-2 schedule (proven: 124 VGPR + 128 acc in unified file, no
// spill; (512,2) = waves-per-eu 2 = 256-reg budget). DO NOT add registers.
// New: SN supertile so an XCD chunk covers ~square (mt x nt) region.
// ===========================================================================

DEVI void stage_half(const u16* __restrict__ G, size_t grow0, int kcol, int Kp,
                     u16* lds, int t)
{
  #pragma unroll
  for (int j = 0; j < 2; ++j){
    const int off16 = j*512 + t;          // 16B units, linear in LDS
    const int rl = off16 >> 3, sl = off16 & 7;
    const u16* gp = G + (grow0 + rl)*(size_t)Kp + kcol + ((sl ^ (rl & 7))*8);
    GLD16(gp, lds + off16*8);
  }
}

template<int RB, int RA>
DEVI void ph_reads(const u16* __restrict__ Ab, const u16* __restrict__ Bb,
                   bf16x8 (&afr)[4][2], bf16x8 (&bfr)[4][2],
                   int wr, int wc, int l4, int l15)
{
  if constexpr (RA >= 0){
    #pragma unroll
    for (int m = 0; m < 4; ++m){
      const int r = wr*128 + RA*64 + m*16 + l15;
      afr[m][0] = *(const bf16x8*)&Ab[r*64 + (((0+l4) ^ (r & 7))*8)];
      afr[m][1] = *(const bf16x8*)&Ab[r*64 + (((4+l4) ^ (r & 7))*8)];
    }
  }
  if constexpr (RB >= 0){
    #pragma unroll
    for (int nn = 0; nn < 2; ++nn){
      const int r = wc*64 + (RB+nn)*16 + l15;
      bfr[RB+nn][0] = *(const bf16x8*)&Bb[r*64 + (((0+l4) ^ (r & 7))*8)];
      bfr[RB+nn][1] = *(const bf16x8*)&Bb[r*64 + (((4+l4) ^ (r & 7))*8)];
    }
  }
}

template<int MH, int NH, int VM>
DEVI void ph_mfma(bf16x8 (&afr)[4][2], bf16x8 (&bfr)[4][2], f32x4 (&acc)[8][4])
{
  __builtin_amdgcn_s_barrier();
  asm volatile("s_waitcnt lgkmcnt(0)" ::: "memory");
  __builtin_amdgcn_sched_barrier(0);
  __builtin_amdgcn_s_setprio(1);
  #pragma unroll
  for (int m = 0; m < 4; ++m)
    #pragma unroll
    for (int nn = 0; nn < 2; ++nn)
      #pragma unroll
      for (int ks = 0; ks < 2; ++ks)
        acc[MH*4+m][NH+nn] = __builtin_amdgcn_mfma_f32_16x16x32_bf16(
            afr[m][ks], bfr[NH+nn][ks], acc[MH*4+m][NH+nn], 0, 0, 0);
  __builtin_amdgcn_s_setprio(0);
  if constexpr (VM == 4){
    __builtin_amdgcn_sched_barrier(0);
    asm volatile("s_waitcnt vmcnt(4)" ::: "memory");
  }
  __builtin_amdgcn_s_barrier();
}

// EPI 0: store f32 C[n*ldc+o]
// EPI 2: store f32 C[n*ldc+o] = leaky(acc*scale[o]+off[o])
// EPI 3: val=leaky(acc+bias[o]); oacc[(q*4+o4)*4+m] += llw[o4*8976+o]*val
template<int EPI>
__global__ __launch_bounds__(512, 2)
void gemm256(const u16* __restrict__ A, const u16* __restrict__ B,
             int Kp, int Nt, int SN, int Mreal, float* __restrict__ C, long long ldc,
             const float* __restrict__ bias, const float* __restrict__ scale,
             const float* __restrict__ off, const float* __restrict__ llw,
             float* __restrict__ oacc)
{
  __shared__ __align__(16) u16 As[2][16384];
  __shared__ __align__(16) u16 Bs[2][16384];
  const int t    = threadIdx.x;
  const int lane = t & 63;
  const int wid  = t >> 6;
  const int wr = wid >> 2, wc = wid & 3;
  const int l4 = lane >> 4, l15 = lane & 15;

  // bijective XCD swizzle (m204 variant)
  const int nwg = gridDim.x;
  const int xc = blockIdx.x & 7, pp = blockIdx.x >> 3;
  const int qq = nwg >> 3, rr = nwg & 7;
  const int wg = (xc < rr ? xc*(qq+1) : rr*(qq+1) + (xc-rr)*qq) + pp;
  // supertile: strips of SN nt-columns, mt-major inside a strip
  const int strip_sz = (nwg / Nt) * SN;
  const int strip = wg / strip_sz, srem = wg % strip_sz;
  const int mt = srem / SN, nt = strip*SN + srem % SN;

  const size_t am0 = (size_t)mt*256;
  const size_t bn0 = (size_t)nt*256;

  f32x4 acc[8][4];
  #pragma unroll
  for (int i = 0; i < 8; ++i)
    #pragma unroll
    for (int j = 0; j < 4; ++j) acc[i][j] = f32x4{0.f,0.f,0.f,0.f};
  bf16x8 afr[4][2], bfr[4][2];

  const int NT2 = Kp >> 6;   // number of 64-wide K tiles (even)
  const int NI  = NT2 >> 1;

  // prologue: tile0 -> buf0 (A0,A1,B0,B1), tile1 -> buf1 (B0,B1)
  stage_half(A, am0+0,   0,  Kp, &As[0][0],    t);
  stage_half(A, am0+128, 0,  Kp, &As[0][8192], t);
  stage_half(B, bn0+0,   0,  Kp, &Bs[0][0],    t);
  stage_half(B, bn0+128, 0,  Kp, &Bs[0][8192], t);
  stage_half(B, bn0+0,   64, Kp, &Bs[1][0],    t);
  stage_half(B, bn0+128, 64, Kp, &Bs[1][8192], t);
  asm volatile("s_waitcnt vmcnt(4)" ::: "memory");
  __builtin_amdgcn_s_barrier();

  for (int i = 0; i < NI; ++i){
    const int k1  = 2*i + 1;
    const int ts0 = (2*i+2 < NT2) ? 2*i+2 : 2*i;
    const int ts1 = (2*i+3 < NT2) ? 2*i+3 : 2*i+1;
    // ph1: read A(b0) rows 0-63 + B(b0) ni01 ; stage A0(b1, k1)
    ph_reads<0,0>(&As[0][0], &Bs[0][0], afr, bfr, wr, wc, l4, l15);
    stage_half(A, am0+0,   k1*64,  Kp, &As[1][0],    t);
    ph_mfma<0,0,-1>(afr, bfr, acc);
    // ph2: read B(b0) ni23 ; stage A1(b1, k1)
    ph_reads<2,-1>(&As[0][0], &Bs[0][0], afr, bfr, wr, wc, l4, l15);
    stage_half(A, am0+128, k1*64,  Kp, &As[1][8192], t);
    ph_mfma<0,2,-1>(afr, bfr, acc);
    // ph3: read A(b0) rows 64-127 ; stage B0(b0, ts0)
    ph_reads<-1,1>(&As[0][0], &Bs[0][0], afr, bfr, wr, wc, l4, l15);
    stage_half(B, bn0+0,   ts0*64, Kp, &Bs[0][0],    t);
    ph_mfma<1,2,-1>(afr, bfr, acc);
    // ph4: stage B1(b0, ts0) ; vmcnt(4)
    stage_half(B, bn0+128, ts0*64, Kp, &Bs[0][8192], t);
    ph_mfma<1,0,4>(afr, bfr, acc);
    // ph5: read A(b1) rows 0-63 + B(b1) ni01 ; stage A0(b0, ts0)
    ph_reads<0,0>(&As[1][0], &Bs[1][0], afr, bfr, wr, wc, l4, l15);
    stage_half(A, am0+0,   ts0*64, Kp, &As[0][0],    t);
    ph_mfma<0,0,-1>(afr, bfr, acc);
    // ph6: read B(b1) ni23 ; stage A1(b0, ts0)
    ph_reads<2,-1>(&As[1][0], &Bs[1][0], afr, bfr, wr, wc, l4, l15);
    stage_half(A, am0+128, ts0*64, Kp, &As[0][8192], t);
    ph_mfma<0,2,-1>(afr, bfr, acc);
    // ph7: read A(b1) rows 64-127 ; stage B0(b1, ts1)
    ph_reads<-1,1>(&As[1][0], &Bs[1][0], afr, bfr, wr, wc, l4, l15);
    stage_half(B, bn0+0,   ts1*64, Kp, &Bs[1][0],    t);
    ph_mfma<1,2,-1>(afr, bfr, acc);
    // ph8: stage B1(b1, ts1) ; vmcnt(4)
    stage_half(B, bn0+128, ts1*64, Kp, &Bs[1][8192], t);
    ph_mfma<1,0,4>(afr, bfr, acc);
  }
  asm volatile("s_waitcnt vmcnt(0)" ::: "memory");

  const int ob0 = mt*256 + wr*128;
  const int nb0 = nt*256 + wc*64;

  if (EPI == 0){
    #pragma unroll
    for (int mi = 0; mi < 8; ++mi){
      const int ob = ob0 + mi*16 + l4*4;
      if (ob < Mreal){
        #pragma unroll
        for (int ni = 0; ni < 4; ++ni){
          const int n = nb0 + ni*16 + l15;
          *(f32x4*)&C[(size_t)n*ldc + ob] = acc[mi][ni];
        }
      }
    }
  } else if (EPI == 2){
    #pragma unroll
    for (int mi = 0; mi < 8; ++mi){
      const int ob = ob0 + mi*16 + l4*4;
      if (ob < Mreal){
        const float sc0=scale[ob],sc1=scale[ob+1],sc2=scale[ob+2],sc3=scale[ob+3];
        const float of0=off[ob],of1=off[ob+1],of2=off[ob+2],of3=off[ob+3];
        #pragma unroll
        for (int ni = 0; ni < 4; ++ni){
          const int n = nb0 + ni*16 + l15;
          f32x4 a = acc[mi][ni];
          f32x4 vv = { lky(a[0]*sc0+of0), lky(a[1]*sc1+of1),
                       lky(a[2]*sc2+of2), lky(a[3]*sc3+of3) };
          *(f32x4*)&C[(size_t)n*ldc + ob] = vv;
        }
      }
    }
  } else { // EPI == 3
    #pragma unroll
    for (int ni = 0; ni < 4; ++ni){
      float s0=0.f, s1=0.f, s2=0.f, s3=0.f;
      #pragma unroll
      for (int mi = 0; mi < 8; ++mi){
        #pragma unroll
        for (int r = 0; r < 4; ++r){
          const int o = ob0 + mi*16 + l4*4 + r;
          if (o < Mreal){
            const float val = lky(acc[mi][ni][r] + bias[o]);
            s0 += llw[o]         * val;
            s1 += llw[8976 + o]  * val;
            s2 += llw[17952 + o] * val;
            s3 += llw[26928 + o] * val;
          }
        }
      }
      const int n = nb0 + ni*16 + l15;
      const int q = n >> 2, m = n & 3;
      float sv[4] = {s0,s1,s2,s3};
      #pragma unroll
      for (int o4 = 0; o4 < 4; ++o4){
        float tt = sv[o4];
        tt += __shfl_xor(tt, 16);
        tt += __shfl_xor(tt, 32);
        if (l4 == 0) atomicAdd(&oacc[(q*4 + o4)*4 + m], tt);
      }
    }
  }
}

// ---------------------------------------------------------------------------
// Old 128x128 GEMM, kept only for the tiny v_pre GEMM (C[o][n]+bias)
// ---------------------------------------------------------------------------
__global__ __launch_bounds__(256)
void gemm_vpre(const u16* __restrict__ A, const u16* __restrict__ B,
               int Kp, int Nt, int Mreal, float* __restrict__ C, long long ldc,
               const float* __restrict__ bias)
{
  __shared__ __align__(16) u16 As[2][4096];
  __shared__ __align__(16) u16 Bs[2][4096];
  const int tid  = threadIdx.x;
  const int lane = tid & 63;
  const int wr   = (tid >> 6) >> 1, wc = (tid >> 6) & 1;
  const int l4   = lane >> 4, l15 = lane & 15;
  const int mt   = blockIdx.x / Nt, nt = blockIdx.x % Nt;

  const size_t arow = (size_t)(mt*128 + (tid>>2)) * Kp + (tid&3)*8;
  const size_t brow = (size_t)(nt*128 + (tid>>2)) * Kp + (tid&3)*8;
  const int    ldst = (tid>>2)*32 + (tid&3)*8;
  const size_t rowskip = (size_t)64 * Kp;

  f32x4 acc[4][4];
  #pragma unroll
  for (int i=0;i<4;i++)
    #pragma unroll
    for (int j=0;j<4;j++) acc[i][j] = f32x4{0.f,0.f,0.f,0.f};

  const int NT = Kp >> 5;
  {
    const u16* a0 = A + arow; const u16* b0 = B + brow;
    GLD16(a0,           &As[0][ldst]);
    GLD16(a0 + rowskip, &As[0][ldst + 2048]);
    GLD16(b0,           &Bs[0][ldst]);
    GLD16(b0 + rowskip, &Bs[0][ldst + 2048]);
  }
  __syncthreads();

  for (int kt=0; kt<NT; ++kt){
    const int cur = kt & 1;
    if (kt + 1 < NT){
      const u16* a0 = A + arow + (size_t)(kt+1)*32;
      const u16* b0 = B + brow + (size_t)(kt+1)*32;
      GLD16(a0,           &As[cur^1][ldst]);
      GLD16(a0 + rowskip, &As[cur^1][ldst + 2048]);
      GLD16(b0,           &Bs[cur^1][ldst]);
      GLD16(b0 + rowskip, &Bs[cur^1][ldst + 2048]);
    }
    bf16x8 af[4], bf[4];
    #pragma unroll
    for (int mi=0;mi<4;mi++)
      af[mi] = *(const bf16x8*)&As[cur][(wr*64 + mi*16 + l15)*32 + l4*8];
    #pragma unroll
    for (int ni=0;ni<4;ni++)
      bf[ni] = *(const bf16x8*)&Bs[cur][(wc*64 + ni*16 + l15)*32 + l4*8];
    #pragma unroll
    for (int mi=0;mi<4;mi++)
      #pragma unroll
      for (int ni=0;ni<4;ni++)
        acc[mi][ni] = __builtin_amdgcn_mfma_f32_16x16x32_bf16(af[mi], bf[ni], acc[mi][ni], 0, 0, 0);
    __syncthreads();
  }

  const int ob0 = mt*128 + wr*64;
  const int nb0 = nt*128 + wc*64;
  #pragma unroll
  for (int mi=0;mi<4;mi++)
    #pragma unroll
    for (int r=0;r<4;r++){
      const int o = ob0 + mi*16 + l4*4 + r;
      if (o < Mreal){
        const float bb = bias[o];
        #pragma unroll
        for (int ni=0;ni<4;ni++){
          const int n = nb0 + ni*16 + l15;
          C[(size_t)o*ldc + n] = acc[mi][ni][r] + bb;
        }
      }
    }
}

// --- f32 -> bf16 padded convert: dst[*][Kp], src rows<srows cols<scols ------
__global__ void k_cvt_pad(const float* __restrict__ src, int srows, int scols,
                          int lds_, int koff, u16* __restrict__ dst, int Kp)
{
  const int r = blockIdx.x;
  const int nch = Kp >> 3;
  for (int ch = threadIdx.x; ch < nch; ch += blockDim.x){
    const int k = ch*8;
    u16 o[8];
    if (r < srows){
      #pragma unroll
      for (int i=0;i<8;i++){
        const int kk = k + i;
        o[i] = (kk < scols) ? f2bf(src[(size_t)r*lds_ + koff + kk]) : (u16)0;
      }
    } else {
      #pragma unroll
      for (int i=0;i<8;i++) o[i] = 0;
    }
    u16x8 vv = { o[0],o[1],o[2],o[3],o[4],o[5],o[6],o[7] };
    *(u16x8*)&dst[(size_t)r*Kp + k] = vv;
  }
}

// --- objB: rows 0..639 = bf16(obj), rows 640..1279 = bf16(|obj|), K pad 4480
__global__ void k_cvt_obj(const float* __restrict__ obj, u16* __restrict__ dst)
{
  const int r = blockIdx.x;
  const int ab = (r >= 640);
  const float* src = obj + (size_t)(ab ? r-640 : r)*4424;
  for (int ch = threadIdx.x; ch < 560; ch += 256){
    const int k = ch*8;
    u16 o[8];
    #pragma unroll
    for (int i=0;i<8;i++){
      const int kk = k+i;
      float f = (kk < 4424) ? src[kk] : 0.f;
      if (ab) f = fabsf(f);
      o[i] = f2bf(f);
    }
    u16x8 vv = { o[0],o[1],o[2],o[3],o[4],o[5],o[6],o[7] };
    *(u16x8*)&dst[(size_t)r*4480 + k] = vv;
  }
}

// --- x (B,256,1024) -> xT bf16 [(b*1024+s)][c] ------------------------------
__global__ void k_xT(const float* __restrict__ x, u16* __restrict__ xT)
{
  __shared__ float t[32][33];
  const int bid = blockIdx.x;
  const int b = bid >> 8; const int cs = (bid >> 5) & 7; const int ss = bid & 31;
  const int tx = threadIdx.x & 31, ty = threadIdx.x >> 5;
  #pragma unroll
  for (int i=0;i<4;i++){
    const int r = ty + i*8;
    t[r][tx] = x[((size_t)(b*256 + cs*32 + r))*1024 + ss*32 + tx];
  }
  __syncthreads();
  #pragma unroll
  for (int i=0;i<4;i++){
    const int r = ty + i*8;
    xT[((size_t)(b*1024 + ss*32 + r))*256 + cs*32 + tx] = f2bf(t[tx][r]);
  }
}

// --- y = fc_w@xr ; mask = sigmoid(y) ----------------------------------------
__global__ void k_ymask(const float* __restrict__ x, const float* __restrict__ fcw,
                        float* __restrict__ y, float* __restrict__ mask)
{
  __shared__ float fc[1024];
  const int b = blockIdx.x >> 2, st = blockIdx.x & 3;
  for (int i=threadIdx.x; i<1024; i+=256) fc[i] = fcw[i];
  __syncthreads();
  const int s = st*256 + threadIdx.x;
  float a0=0,a1=0,a2=0,a3=0;
  for (int c=0;c<256;c++){
    const float xv = x[((size_t)(b*256+c))*1024 + s];
    a0 += fc[c]*xv; a1 += fc[256+c]*xv; a2 += fc[512+c]*xv; a3 += fc[768+c]*xv;
  }
  const size_t base = (size_t)(b*4)*1024 + s;
  y[base]        = a0; mask[base]        = 1.f/(1.f+expf(-a0));
  y[base+1024]   = a1; mask[base+1024]   = 1.f/(1.f+expf(-a1));
  y[base+2048]   = a2; mask[base+2048]   = 1.f/(1.f+expf(-a2));
  y[base+3072]   = a3; mask[base+3072]   = 1.f/(1.f+expf(-a3));
}

__global__ void k_out1(const float* __restrict__ y, float* __restrict__ out1){
  const int bn = blockIdx.x;
  float m = -3.4e38f;
  for (int s=threadIdx.x; s<1024; s+=256) m = fmaxf(m, y[(size_t)bn*1024+s]);
  for (int o=32;o;o>>=1) m = fmaxf(m, __shfl_xor(m,o));
  __shared__ float red[4];
  if ((threadIdx.x&63)==0) red[threadIdx.x>>6] = m;
  __syncthreads();
  if (threadIdx.x==0) out1[bn] = fmaxf(fmaxf(red[0],red[1]),fmaxf(red[2],red[3]));
}

// --- v[b,j,m] = sum_s vpreT[j][b*1024+s]*mask[b,m,s] ------------------------
__global__ void k_v(const float* __restrict__ vpreT, const float* __restrict__ mask,
                    float* __restrict__ v){
  const int b = blockIdx.x >> 7, j = blockIdx.x & 127;
  float a[4]={0,0,0,0};
  for (int s=threadIdx.x; s<1024; s+=256){
    const float pv = vpreT[(size_t)j*8192 + b*1024 + s];
    #pragma unroll
    for (int m=0;m<4;m++) a[m] += pv * mask[((size_t)(b*4+m))*1024 + s];
  }
  __shared__ float red[4][5];
  #pragma unroll
  for (int m=0;m<4;m++){
    float t=a[m];
    for (int o=32;o;o>>=1) t += __shfl_xor(t,o);
    if ((threadIdx.x&63)==0) red[m][threadIdx.x>>6]=t;
  }
  __syncthreads();
  if (threadIdx.x<4)
    v[(size_t)(b*128+j)*4 + threadIdx.x] =
      red[threadIdx.x][0]+red[threadIdx.x][1]+red[threadIdx.x][2]+red[threadIdx.x][3];
}

// --- lv[b,j,n] = leaky(sum_m A[n,m]*v[b,j,m]) -------------------------------
__global__ void k_lv(const float* __restrict__ Am, const float* __restrict__ v,
                     float* __restrict__ lv){
  const int idx = blockIdx.x*256 + threadIdx.x;
  if (idx < 1024){
    #pragma unroll
    for (int n=0;n<4;n++){
      float s=0;
      #pragma unroll
      for (int m=0;m<4;m++) s += Am[n*4+m]*v[idx*4+m];
      lv[idx*4+n] = lky(s);
    }
  }
}

// --- sV[b,o,n] = sum_j sw_w[o,8848+j]*lv[b,j,n] -----------------------------
__global__ void k_sV(const float* __restrict__ sw, const float* __restrict__ lv,
                     float* __restrict__ sV){
  __shared__ float l[4096];
  for (int i=threadIdx.x; i<4096; i+=256) l[i]=lv[i];
  __syncthreads();
  const int o = blockIdx.x*256 + threadIdx.x;
  if (o >= 8976) return;
  float acc[8][4] = {};
  const float* row = sw + (size_t)o*8976 + 8848;
  for (int j=0;j<128;j++){
    const float wv = row[j];
    #pragma unroll
    for (int b=0;b<8;b++){
      const float* lb = &l[(b*128+j)*4];
      #pragma unroll
      for (int n=0;n<4;n++) acc[b][n] += wv*lb[n];
    }
  }
  #pragma unroll
  for (int b=0;b<8;b++){
    f32x4 vv = {acc[b][0],acc[b][1],acc[b][2],acc[b][3]};
    *(f32x4*)&sV[((size_t)b*8976 + o)*4] = vv;
  }
}

// --- BN fold ----------------------------------------------------------------
__global__ void k_so(const float* __restrict__ cgb, const float* __restrict__ g,
                     const float* __restrict__ b2, const float* __restrict__ m,
                     const float* __restrict__ vvar, float* __restrict__ so){
  const int o = blockIdx.x*256+threadIdx.x;
  if (o<8976){
    const float sc = g[o]*rsqrtf(vvar[o]+1e-5f);
    so[o]=sc; so[8976+o] = (cgb[o]-m[o])*sc + b2[o];
  }
}

// --- glbB (bf16 mean_n hg, K pad 9088) + t2[q,o',n] = sum_c co_w2[o',c]*hg --
// P1/P2 reconstructed from U directly (no P12 buffer):
//   p1 = U[i1][c] + U[i2][8976+c];  p2 = U[640+i1][c] + U[640+i2][8976+c]
__global__ void k_glb_t2(const float* __restrict__ U, const float* __restrict__ obj,
                         const int* __restrict__ rel,
                         const float* __restrict__ sV, const float* __restrict__ swb,
                         const float* __restrict__ v, const float* __restrict__ Am,
                         const float* __restrict__ cow, u16* __restrict__ glbB,
                         float* __restrict__ t2)
{
  const int q = blockIdx.x; const int b = q >> 7;
  const int i1 = rel[q*2], i2 = rel[q*2+1];
  const float* u1  = U + (size_t)i1*17952;
  const float* u2  = U + (size_t)i2*17952 + 8976;
  const float* u1a = U + (size_t)(640+i1)*17952;
  const float* u2a = U + (size_t)(640+i2)*17952 + 8976;
  const float* o1 = obj + (size_t)i1*4424;
  const float* o2 = obj + (size_t)i2*4424;
  float rA[4], aA[4];
  #pragma unroll
  for (int n=0;n<4;n++){
    const float s = Am[n*4]+Am[n*4+1]+Am[n*4+2]+Am[n*4+3];
    rA[n]=0.6f*s; aA[n]=0.4f*fabsf(s);
  }
  float t2a[16] = {};
  for (int c = threadIdx.x; c < 9088; c += 256){
    if (c < 8976){
      const float p1 = u1[c] + u2[c];
      const float p2 = u1a[c] + u2a[c];
      const f32x4 sv = *(const f32x4*)&sV[((size_t)b*8976 + c)*4];
      const float sb = swb[c];
      const float gs = (c < 4424) ? o1[c] : (c < 8848) ? o2[c-4424] : 0.f;
      float hg[4]; float sum = 0.f;
      #pragma unroll
      for (int n=0;n<4;n++){
        const float xs2 = lky(rA[n]*p1 + aA[n]*p2 + sv[n] + sb);
        const float g = (c < 8848) ? gs : v[((size_t)b*128 + (c-8848))*4 + n];
        hg[n] = g + xs2; sum += hg[n];
      }
      glbB[(size_t)q*9088 + c] = f2bf(0.25f*sum);
      #pragma unroll
      for (int o4=0;o4<4;o4++){
        const float cw = cow[(size_t)o4*17952 + 8976 + c];
        #pragma unroll
        for (int n=0;n<4;n++) t2a[o4*4+n] += cw*hg[n];
      }
    } else {
      glbB[(size_t)q*9088 + c] = 0;
    }
  }
  __shared__ float red[16][5];
  #pragma unroll
  for (int i=0;i<16;i++){
    float t = t2a[i];
    for (int o=32;o;o>>=1) t += __shfl_xor(t,o);
    if ((threadIdx.x&63)==0) red[i][threadIdx.x>>6]=t;
  }
  __syncthreads();
  if (threadIdx.x < 16)
    t2[q*16+threadIdx.x] = red[threadIdx.x][0]+red[threadIdx.x][1]
                          +red[threadIdx.x][2]+red[threadIdx.x][3];
}

// --- adj[q,a,m] = sigmoid(co1[q,a] + t2[q,a,m] + co_b[a]) -------------------
__global__ void k_adj(const float* __restrict__ glb2, const float* __restrict__ cow,
                      const float* __restrict__ t2, const float* __restrict__ cob,
                      float* __restrict__ adj)
{
  const int q = blockIdx.x;
  float a[4]={0,0,0,0};
  for (int c=threadIdx.x; c<8976; c+=256){
    const float g = glb2[(size_t)q*8976+c];
    #pragma unroll
    for (int o=0;o<4;o++) a[o] += cow[(size_t)o*17952 + c]*g;
  }
  __shared__ float red[4][5]; __shared__ float co1[4];
  #pragma unroll
  for (int i=0;i<4;i++){
    float t=a[i]; for (int o=32;o;o>>=1) t += __shfl_xor(t,o);
    if ((threadIdx.x&63)==0) red[i][threadIdx.x>>6]=t;
  }
  __syncthreads();
  if (threadIdx.x<4)
    co1[threadIdx.x]=red[threadIdx.x][0]+red[threadIdx.x][1]+red[threadIdx.x][2]+red[threadIdx.x][3];
  __syncthreads();
  if (threadIdx.x<16){
    const int a_=threadIdx.x>>2, m=threadIdx.x&3;
    const float t = co1[a_] + t2[q*16 + a_*4 + m] + cob[a_];
    adj[q*16 + a_*4 + m] = 1.f/(1.f+expf(-t));
  }
}

// --- hd_b[(q*4+m)][c] = bf16(leaky(sum_n hg[q,c,n]*adj[q,n,m])), K pad 9088 -
__global__ void k_hd(const float* __restrict__ U, const float* __restrict__ obj,
                     const int* __restrict__ rel,
                     const float* __restrict__ sV, const float* __restrict__ swb,
                     const float* __restrict__ v, const float* __restrict__ Am,
                     const float* __restrict__ adj, u16* __restrict__ hdb)
{
  const int q = blockIdx.x; const int b = q>>7;
  const int i1 = rel[q*2], i2 = rel[q*2+1];
  const float* u1  = U + (size_t)i1*17952;
  const float* u2  = U + (size_t)i2*17952 + 8976;
  const float* u1a = U + (size_t)(640+i1)*17952;
  const float* u2a = U + (size_t)(640+i2)*17952 + 8976;
  const float* o1 = obj + (size_t)i1*4424;
  const float* o2 = obj + (size_t)i2*4424;
  float rA[4], aA[4];
  #pragma unroll
  for (int n=0;n<4;n++){
    const float s = Am[n*4]+Am[n*4+1]+Am[n*4+2]+Am[n*4+3];
    rA[n]=0.6f*s; aA[n]=0.4f*fabsf(s);
  }
  __shared__ float aj[16];
  if (threadIdx.x<16) aj[threadIdx.x] = adj[q*16+threadIdx.x];
  __syncthreads();
  float ajr[16];
  #pragma unroll
  for (int i=0;i<16;i++) ajr[i]=aj[i];
  for (int c=threadIdx.x; c<9088; c+=256){
    if (c<8976){
      const float p1 = u1[c] + u2[c];
      const float p2 = u1a[c] + u2a[c];
      const f32x4 sv = *(const f32x4*)&sV[((size_t)b*8976 + c)*4];
      const float sb = swb[c];
      const float gs = (c < 4424) ? o1[c] : (c < 8848) ? o2[c-4424] : 0.f;
      float hg[4];
      #pragma unroll
      for (int n=0;n<4;n++){
        const float xs2 = lky(rA[n]*p1 + aA[n]*p2 + sv[n] + sb);
        const float g = (c < 8848) ? gs : v[((size_t)b*128 + (c-8848))*4 + n];
        hg[n] = g + xs2;
      }
      #pragma unroll
      for (int m=0;m<4;m++){
        const float hv = lky(hg[0]*ajr[m] + hg[1]*ajr[4+m] + hg[2]*ajr[8+m] + hg[3]*ajr[12+m]);
        hdb[((size_t)(q*4+m))*9088 + c] = f2bf(hv);
      }
    } else {
      #pragma unroll
      for (int m=0;m<4;m++) hdb[((size_t)(q*4+m))*9088 + c] = 0;
    }
  }
}

// --- final ------------------------------------------------------------------
__global__ void k_final(const float* __restrict__ o2f, const float* __restrict__ out1,
                        const float* __restrict__ llb, const float* __restrict__ mm,
                        float* __restrict__ out)
{
  const int idx = blockIdx.x*256+threadIdx.x;
  if (idx < 4096){
    const int q = idx>>2, o = idx&3, b = q>>7;
    float s=0.f;
    #pragma unroll
    for (int m=0;m<4;m++) s += lky(o2f[(q*4+o)*4+m] + llb[o]) * mm[o*4+m];
    out[idx] = 0.5f*(out1[b*4+o] + s);
  }
}

extern "C" void kernel_launch(void* const* d_in, const int* in_sizes, int n_in,
                              void* d_out, int out_size, void* d_ws, size_t ws_size,
                              hipStream_t stream)
{
  const float* x    = (const float*)d_in[0];
  const int*   rel  = (const int*)d_in[1];
  const float* obj  = (const float*)d_in[2];
  const float* fcw  = (const float*)d_in[3];
  const float* ctw  = (const float*)d_in[4];
  const float* ctb  = (const float*)d_in[5];
  const float* Am   = (const float*)d_in[6];
  const float* sww  = (const float*)d_in[7];
  const float* swb  = (const float*)d_in[8];
  const float* cgw  = (const float*)d_in[9];
  const float* cgb  = (const float*)d_in[10];
  const float* bng  = (const float*)d_in[11];
  const float* bnb  = (const float*)d_in[12];
  const float* bnm  = (const float*)d_in[13];
  const float* bnv  = (const float*)d_in[14];
  const float* cow  = (const float*)d_in[15];
  const float* cob  = (const float*)d_in[16];
  const float* dww  = (const float*)d_in[17];
  const float* dwb  = (const float*)d_in[18];
  const float* llw  = (const float*)d_in[19];
  const float* llb  = (const float*)d_in[20];
  const float* mm   = (const float*)d_in[21];
  float* out = (float*)d_out;
  (void)in_sizes; (void)n_in; (void)out_size; (void)ws_size;

  char* ws = (char*)d_ws;
  size_t off = 0;
  auto alloc = [&](size_t bytes)->char*{
    char* p = ws + off; off = (off + bytes + 255) & ~(size_t)255; return p;
  };
  u16*   Wb    = (u16*)  alloc((size_t)9216*9088*2);   // also holds 18176x4480
  float* U     = (float*)alloc((size_t)1280*17952*4);  // live through k_hd
  u16*   glbB  = (u16*)  alloc((size_t)1024*9088*2);
  u16*   hdb   = (u16*)  alloc((size_t)4096*9088*2);
  u16*   objB  = (u16*)  alloc((size_t)1280*4480*2);
  float* glb2  = (float*)alloc((size_t)1024*8976*4);
  u16*   xT    = (u16*)  alloc((size_t)8192*256*2);
  u16*   ctwb  = (u16*)  alloc((size_t)128*256*2);
  float* y     = (float*)alloc((size_t)32768*4);
  float* mask  = (float*)alloc((size_t)32768*4);
  float* out1  = (float*)alloc((size_t)32*4);
  float* vpreT = (float*)alloc((size_t)128*8192*4);
  float* v     = (float*)alloc((size_t)4096*4);
  float* lv    = (float*)alloc((size_t)4096*4);
  float* sV    = (float*)alloc((size_t)287232*4);
  float* so    = (float*)alloc((size_t)2*8976*4);
  float* t2    = (float*)alloc((size_t)16384*4);
  float* adj   = (float*)alloc((size_t)16384*4);
  float* o2f   = (float*)alloc((size_t)16384*4);

  // stage 1: small precomputes
  k_xT<<<dim3(2048), dim3(256), 0, stream>>>(x, xT);
  k_cvt_pad<<<dim3(128), dim3(256), 0, stream>>>(ctw, 128, 256, 256, 0, ctwb, 256);
  k_ymask<<<dim3(32), dim3(256), 0, stream>>>(x, fcw, y, mask);
  k_out1<<<dim3(32), dim3(256), 0, stream>>>(y, out1);
  gemm_vpre<<<dim3(64), dim3(256), 0, stream>>>(
      ctwb, xT, 256, 64, 128, vpreT, (long long)8192, ctb);
  k_v<<<dim3(1024), dim3(256), 0, stream>>>(vpreT, mask, v);

  // stage 2: U = [W_F_left; W_F_right] @ [obj; |obj|]^T
  k_cvt_obj<<<dim3(1280), dim3(256), 0, stream>>>(obj, objB);
  k_cvt_pad<<<dim3(8976), dim3(256), 0, stream>>>(sww, 8976, 4424, 8976, 0, Wb, 4480);
  k_cvt_pad<<<dim3(9200), dim3(256), 0, stream>>>(sww, 8976, 4424, 8976, 4424,
                                                  Wb + (size_t)8976*4480, 4480);
  gemm256<0><<<dim3(71*5), dim3(512), 0, stream>>>(
      Wb, objB, 4480, 5, 5, 17952, U, (long long)17952,
      nullptr, nullptr, nullptr, nullptr, nullptr);

  // stage 3: sV, glb, t2  (reads U directly via rel)
  k_lv<<<dim3(4), dim3(256), 0, stream>>>(Am, v, lv);
  k_sV<<<dim3(36), dim3(256), 0, stream>>>(sww, lv, sV);
  k_glb_t2<<<dim3(1024), dim3(256), 0, stream>>>(U, obj, rel, sV, swb, v, Am,
                                                 cow, glbB, t2);

  // stage 4: GEMM2  glb2 = leaky(BN(cg_w @ glb + cg_b))
  k_cvt_pad<<<dim3(9216), dim3(256), 0, stream>>>(cgw, 8976, 8976, 8976, 0, Wb, 9088);
  k_so<<<dim3(36), dim3(256), 0, stream>>>(cgb, bng, bnb, bnm, bnv, so);
  gemm256<2><<<dim3(36*4), dim3(512), 0, stream>>>(
      Wb, glbB, 9088, 4, 4, 8976, glb2, (long long)8976,
      nullptr, so, so + 8976, nullptr, nullptr);

  // stage 5: adj, hd  (k_hd reads U directly via rel)
  k_adj<<<dim3(1024), dim3(256), 0, stream>>>(glb2, cow, t2, cob, adj);
  k_cvt_pad<<<dim3(9216), dim3(256), 0, stream>>>(dww, 8976, 8976, 8976, 0, Wb, 9088);
  k_hd<<<dim3(1024), dim3(256), 0, stream>>>(U, obj, rel, sV, swb, v, Am, adj, hdb);

  // stage 6: GEMM3 fused with ll_w reduction (SN=8 supertile)
  hipMemsetAsync(o2f, 0, (size_t)16384*4, stream);
  gemm256<3><<<dim3(36*16), dim3(512), 0, stream>>>(
      Wb, hdb, 9088, 16, 8, 8976, nullptr, 0, dwb,
      nullptr, nullptr, llw, o2f);

  // stage 7: final combine
  k_final<<<dim3(16), dim3(256), 0, stream>>>(o2f, out1, llb, mm, out);
}